// Round 10
// baseline (1328.654 us; speedup 1.0000x reference)
//
#include <hip/hip_runtime.h>

// B=4, Cin=Cout=64, H=W=128, K=9, PAD=1. NCHW fp32.
//
// lgkm-only barrier: LDS producer->consumer needs lgkmcnt(0) only; global
// prefetch loads stay in flight across it (vmcnt wait lands at the use).
#define BAR_LGKM()                                         \
  do {                                                     \
    asm volatile("s_waitcnt lgkmcnt(0)" ::: "memory");     \
    __builtin_amdgcn_s_barrier();                          \
  } while (0)

// XCD-aware swizzle: 1024 blocks, 8 XCDs, dispatch round-robins bid%8.
// Each XCD gets a contiguous 128-block chunk -> gather footprint ~2.4MB
// fits the XCD's 4MB L2. (Verified round 4: FETCH 52.6 MB -> 12.7 MB.)
__device__ __forceinline__ int swz_block(int bid) {
  return ((bid & 7) << 7) + (bid >> 3);
}

// Workspace layout (floats):
//   wt1  @ 0       (36864)  main weights layer1, [c][og][k][oi] (og=o/8, oi=o%8)
//   wt2  @ 36864   (36864)
//   wo1  @ 73728   (10368)  offset-conv weights layer1, [c][t][j] (j=0..17)
//   wo2  @ 84096   (10368)
//   bn1  @ 94464   (128)    scale[64], shift[64]
//   bn2  @ 94592   (128)
//   offb @ 94720   (1179648)  4*18*16384
//   hbuf @ 1274368 (4194304)  4*64*16384

// ---------------- prep: weight relayouts + BN constants ---------------------
__global__ __launch_bounds__(256) void prep_kernel(
    const float* __restrict__ w1, const float* __restrict__ w2,
    const float* __restrict__ woff1, const float* __restrict__ woff2,
    const float* __restrict__ g1, const float* __restrict__ be1,
    const float* __restrict__ m1, const float* __restrict__ v1,
    const float* __restrict__ g2, const float* __restrict__ be2,
    const float* __restrict__ m2, const float* __restrict__ v2,
    float* __restrict__ ws) {
  float* wt1 = ws;
  float* wt2 = ws + 36864;
  float* wo1 = ws + 73728;
  float* wo2 = ws + 84096;
  float* bn1 = ws + 94464;
  float* bn2 = ws + 94592;
  int idx = blockIdx.x * 256 + threadIdx.x;
  if (idx < 73728) {
    int t = (idx < 36864) ? idx : idx - 36864;
    const float* w = (idx < 36864) ? w1 : w2;
    float* wt = (idx < 36864) ? wt1 : wt2;
    int oi = t & 7;
    int rest = t >> 3;             // (c*8+og)*9 + k
    int k = rest % 9;
    int cog = rest / 9;
    int og = cog & 7, c = cog >> 3;
    int o = og * 8 + oi;
    wt[t] = w[(o * 64 + c) * 9 + k];
  } else if (idx < 94464) {
    int u = idx - 73728;
    int t2 = (u < 10368) ? u : u - 10368;
    const float* w = (u < 10368) ? woff1 : woff2;
    float* wo = (u < 10368) ? wo1 : wo2;
    int j = t2 % 18;
    int v = t2 / 18;               // c*9 + t
    int tt = v % 9;
    int c = v / 9;
    wo[t2] = w[(j * 64 + c) * 9 + tt];
  } else if (idx < 94528) {
    int o = idx - 94464;
    float s = g1[o] * rsqrtf(v1[o] + 1e-5f);
    bn1[o] = s;
    bn1[64 + o] = be1[o] - m1[o] * s;
  } else if (idx < 94592) {
    int o = idx - 94528;
    float s = g2[o] * rsqrtf(v2[o] + 1e-5f);
    bn2[o] = s;
    bn2[64 + o] = be2[o] - m2[o] * s;
  }
}

// ---------------- offset conv: 3x3, 64 -> 18 ch, zero pad -------------------
// Round-4 structure + weights staged to LDS (sWo) with one-phase-ahead
// register prefetch; compute reads weights via wave-uniform ds_read_b32
// broadcast instead of SGPR-chunked s_load chains (the suspected serial
// K$-latency stall).
__global__ __launch_bounds__(512, 8) void conv_off_kernel(
    const float* __restrict__ xin, const float* __restrict__ wofft,
    const float* __restrict__ boff, float* __restrict__ off) {
  __shared__ float halo[2][792];   // [buf][plane*198 + pos], 4 planes/stage
  __shared__ float sWo[2][648];    // [buf][ (c_local*162) + t*18 + j ]
  int tid = threadIdx.x;
  int pxl = tid & 63;
  int og = tid >> 6;
  int ogu = __builtin_amdgcn_readfirstlane(og);   // wave-uniform
  int p0 = swz_block(blockIdx.x) * 64;
  int b = p0 >> 14, hw0 = p0 & 16383;
  int h = hw0 >> 7, w0 = hw0 & 127;

  bool sv = tid < 396;
  int pp = (tid >= 198) ? 1 : 0;   // which of 2 plane-slots this thread loads
  int pos = tid - pp * 198;
  int r = pos / 66, cc = pos - r * 66;
  int yy = h + r - 1, xx = w0 + cc - 1;
  bool inb = sv && (yy >= 0) && (yy < 128) && (xx >= 0) && (xx < 128);
  int ofs = (yy << 7) + xx;        // plane-relative
  const float* xb0 = xin + ((size_t)(b * 64) << 14);

  // prologue: planes 0..3 (thread covers planes pp and 2+pp at its pos)
  float stg0 = inb ? xb0[((size_t)pp << 14) + ofs] : 0.f;
  float stg1 = inb ? xb0[((size_t)(2 + pp) << 14) + ofs] : 0.f;
  // weights for phase 0 (c=0..3): 648 floats via 324 threads x float2
  bool wl = tid < 324;
  float2 wg = wl ? ((const float2*)wofft)[tid] : make_float2(0.f, 0.f);

  // j-channel assignment: og 0,1 -> 3 outputs; og 2..7 -> 2 outputs.
  int jbase = (ogu < 2) ? ogu * 3 : 6 + (ogu - 2) * 2;
  int nj = (ogu < 2) ? 3 : 2;
  int jc2 = jbase + 2;
  if (jc2 > 17) jc2 = 17;          // clamp (result unused when nj==2)

  float acc[3] = {0.f, 0.f, 0.f};

#pragma unroll 1
  for (int cg = 0; cg < 64; cg += 4) {
    int bufi = (cg >> 2) & 1;
    if (sv) {
      halo[bufi][pp * 198 + pos] = stg0;
      halo[bufi][(2 + pp) * 198 + pos] = stg1;
    }
    if (wl) *(float2*)&sWo[bufi][tid << 1] = wg;
    if (cg < 60) {
      stg0 = inb ? xb0[((size_t)(cg + 4 + pp) << 14) + ofs] : 0.f;
      stg1 = inb ? xb0[((size_t)(cg + 6 + pp) << 14) + ofs] : 0.f;
      if (wl) wg = ((const float2*)(wofft + (cg + 4) * 162))[tid];
    }
    BAR_LGKM();
    const float* hb = halo[bufi];
#pragma unroll
    for (int p = 0; p < 4; ++p) {
      const float* wc = &sWo[bufi][p * 162];   // uniform LDS broadcast reads
#pragma unroll
      for (int t = 0; t < 9; ++t) {
        float v = hb[p * 198 + (t / 3) * 66 + pxl + (t % 3)];
        acc[0] = fmaf(v, wc[t * 18 + jbase], acc[0]);
        acc[1] = fmaf(v, wc[t * 18 + jbase + 1], acc[1]);
        acc[2] = fmaf(v, wc[t * 18 + jc2], acc[2]);
      }
    }
  }
#pragma unroll
  for (int i = 0; i < 3; ++i) {
    if (i < nj) {
      int j = jbase + i;
      off[((size_t)(b * 18 + j) << 14) + hw0 + pxl] = acc[i] + boff[j];
    }
  }
}

// ---------------- fused deformable sample + einsum + BN + ReLU --------------
// Round-7 structure (folded coeffs, incrementing pointers, depth-1 prefetch
// across lgkm-only barrier, XCD swizzle) + weights staged to LDS (sW) with
// one-c-ahead register prefetch; einsum reads weights via wave-uniform
// ds_read_b128 broadcast (removes SGPR-chunked s_load serial chains).
__global__ __launch_bounds__(512, 8) void dcn_main_kernel(
    const float* __restrict__ xin, const float* __restrict__ off,
    const float* __restrict__ wt, const float* __restrict__ bn,
    float* __restrict__ out) {
  __shared__ float sbuf[2][576];
  __shared__ __align__(16) float sW[2][576];   // [buf][og*72 + k*8 + oi]
  int tid = threadIdx.x;
  int pxl = tid & 63;
  int og = tid >> 6;
  int ogu = __builtin_amdgcn_readfirstlane(og);
  int p0 = swz_block(blockIdx.x) * 64;
  int b = p0 >> 14, hw0 = p0 & 16383;
  int h = hw0 >> 7, w0 = hw0 & 127;
  const float* xb = xin + ((size_t)b << 20);

  bool act1 = (tid & 7) == 0;      // slot1 handled by 1/8 of threads
  int s1 = 512 + (tid >> 3);       // slot id 512..575 (k=8)
  bool wl = tid < 144;             // weight-staging threads (144*4 = 576)

  // --- per-slot params: folded coeffs (x-select baked in) + row pointers ---
  float q[2][4];                   // [slot][{t0.x,t0.y,t1.x,t1.y} coeff]
  const float* pa[2];              // row y0 float2 base (per-lane), plane 0
  const float* pb[2];              // row y1

#pragma unroll
  for (int j = 0; j < 2; ++j) {
    bool a = (j == 0) || act1;
    int s = (j == 0) ? tid : s1;
    int k = s >> 6;
    int pxs = s & 63;
    int hw = hw0 + pxs;
    float dy = a ? off[((size_t)(b * 18 + 2 * k) << 14) + hw] : 0.f;
    float dx = a ? off[((size_t)(b * 18 + 2 * k + 1) << 14) + hw] : 0.f;
    float py = (float)(h + k / 3 - 1) + dy;
    float pxf = (float)(w0 + pxs + k % 3 - 1) + dx;
    float y0f = floorf(py), x0f = floorf(pxf);
    float wy1 = py - y0f, wx1 = pxf - x0f;
    float wy0 = 1.f - wy1, wx0 = 1.f - wx1;
    int y0 = (int)y0f, x0 = (int)x0f;
    int y1 = y0 + 1, x1 = x0 + 1;
    bool vy0 = (y0 >= 0) && (y0 <= 127);
    bool vy1 = (y1 >= 0) && (y1 <= 127);
    bool vx0 = (x0 >= 0) && (x0 <= 127);
    bool vx1 = (x1 >= 0) && (x1 <= 127);
    float pw0 = (vy0 && vx0) ? wy0 * wx0 : 0.f;
    float pw1 = (vy0 && vx1) ? wy0 * wx1 : 0.f;
    float pw2 = (vy1 && vx0) ? wy1 * wx0 : 0.f;
    float pw3 = (vy1 && vx1) ? wy1 * wx1 : 0.f;
    int y0c = min(max(y0, 0), 127), y1c = min(max(y1, 0), 127);
    int xb2 = min(max(x0, 0), 126);
    bool se0 = (x0 == xb2);        // tap(x0) is .x of the pair
    bool se1 = (x0 + 1 == xb2);    // tap(x0+1) is .x of the pair (x0==-1 case)
    // fold selects: coeff(.x) = se?pw ; coeff(.y) = !se?pw. Whenever the
    // "wrong" element is picked, the corresponding pw is already 0.
    q[j][0] = (se0 ? pw0 : 0.f) + (se1 ? pw1 : 0.f);
    q[j][1] = (se0 ? 0.f : pw0) + (se1 ? 0.f : pw1);
    q[j][2] = (se0 ? pw2 : 0.f) + (se1 ? pw3 : 0.f);
    q[j][3] = (se0 ? 0.f : pw2) + (se1 ? 0.f : pw3);
    pa[j] = xb + ((y0c << 7) + xb2);
    pb[j] = xb + ((y1c << 7) + xb2);
  }

  // prologue: taps for c=0; weights for c=0; advance pointers to plane 1
  float2 t0a = *(const float2*)pa[0];
  float2 t1a = *(const float2*)pb[0];
  float2 t0b = act1 ? *(const float2*)pa[1] : make_float2(0.f, 0.f);
  float2 t1b = act1 ? *(const float2*)pb[1] : make_float2(0.f, 0.f);
  pa[0] += 16384; pb[0] += 16384; pa[1] += 16384; pb[1] += 16384;
  float4 wreg = wl ? *(const float4*)(wt + (tid << 2))
                   : make_float4(0.f, 0.f, 0.f, 0.f);

  float acc[8];
#pragma unroll
  for (int oi = 0; oi < 8; ++oi) acc[oi] = 0.f;

#pragma unroll 1
  for (int c = 0; c < 64; ++c) {
    int buf = c & 1;
    // stage this c's weights (prefetched last iter) into LDS
    if (wl) *(float4*)&sW[buf][tid << 2] = wreg;
    // blend + stash to LDS (4 FMA, no selects)
    sbuf[buf][tid] = fmaf(q[0][0], t0a.x,
                     fmaf(q[0][1], t0a.y,
                     fmaf(q[0][2], t1a.x, q[0][3] * t1a.y)));
    if (act1) {
      sbuf[buf][s1] = fmaf(q[1][0], t0b.x,
                      fmaf(q[1][1], t0b.y,
                      fmaf(q[1][2], t1b.x, q[1][3] * t1b.y)));
    }
    // prefetch taps + weights for c+1 (in flight across the lgkm barrier)
    if (c < 63) {
      t0a = *(const float2*)pa[0];
      t1a = *(const float2*)pb[0];
      if (act1) {
        t0b = *(const float2*)pa[1];
        t1b = *(const float2*)pb[1];
      }
      pa[0] += 16384; pb[0] += 16384; pa[1] += 16384; pb[1] += 16384;
      if (wl) wreg = *(const float4*)(wt + (c + 1) * 576 + (tid << 2));
    }
    BAR_LGKM();
    // einsum: weights via wave-uniform ds_read_b128 broadcast (no s_load
    // SGPR-chunked chains)
    const float* wb = &sW[buf][ogu * 72];
#pragma unroll
    for (int k = 0; k < 9; ++k) {
      float4 wA = *(const float4*)(wb + k * 8);
      float4 wB = *(const float4*)(wb + k * 8 + 4);
      float sval = sbuf[buf][k * 64 + pxl];
      acc[0] = fmaf(sval, wA.x, acc[0]);
      acc[1] = fmaf(sval, wA.y, acc[1]);
      acc[2] = fmaf(sval, wA.z, acc[2]);
      acc[3] = fmaf(sval, wA.w, acc[3]);
      acc[4] = fmaf(sval, wB.x, acc[4]);
      acc[5] = fmaf(sval, wB.y, acc[5]);
      acc[6] = fmaf(sval, wB.z, acc[6]);
      acc[7] = fmaf(sval, wB.w, acc[7]);
    }
  }

#pragma unroll
  for (int oi = 0; oi < 8; ++oi) {
    int o = ogu * 8 + oi;
    float rres = fmaf(acc[oi], bn[o], bn[64 + o]);
    out[((size_t)(b * 64 + o) << 14) + hw0 + pxl] = fmaxf(rres, 0.f);
  }
}

extern "C" void kernel_launch(void* const* d_in, const int* in_sizes, int n_in,
                              void* d_out, int out_size, void* d_ws, size_t ws_size,
                              hipStream_t stream) {
  const float* x      = (const float*)d_in[0];
  const float* w_off1 = (const float*)d_in[1];
  const float* b_off1 = (const float*)d_in[2];
  const float* w1     = (const float*)d_in[3];
  const float* g1     = (const float*)d_in[4];
  const float* be1    = (const float*)d_in[5];
  const float* m1     = (const float*)d_in[6];
  const float* v1     = (const float*)d_in[7];
  const float* w_off2 = (const float*)d_in[8];
  const float* b_off2 = (const float*)d_in[9];
  const float* w2     = (const float*)d_in[10];
  const float* g2     = (const float*)d_in[11];
  const float* be2    = (const float*)d_in[12];
  const float* m2     = (const float*)d_in[13];
  const float* v2     = (const float*)d_in[14];
  float* out = (float*)d_out;

  float* ws   = (float*)d_ws;
  float* wt1  = ws;
  float* wt2  = ws + 36864;
  float* wo1  = ws + 73728;
  float* wo2  = ws + 84096;
  float* bn1  = ws + 94464;
  float* bn2  = ws + 94592;
  float* offb = ws + 94720;
  float* hbuf = ws + 1274368;

  prep_kernel<<<370, 256, 0, stream>>>(w1, w2, w_off1, w_off2,
                                       g1, be1, m1, v1, g2, be2, m2, v2, ws);

  conv_off_kernel<<<1024, 512, 0, stream>>>(x, wo1, b_off1, offb);
  dcn_main_kernel<<<1024, 512, 0, stream>>>(x, offb, wt1, bn1, hbuf);

  conv_off_kernel<<<1024, 512, 0, stream>>>(hbuf, wo2, b_off2, offb);
  dcn_main_kernel<<<1024, 512, 0, stream>>>(hbuf, offb, wt2, bn2, out);
}

// Round 11
// 392.835 us; speedup vs baseline: 3.3822x; 3.3822x over previous
//
#include <hip/hip_runtime.h>

// B=4, Cin=Cout=64, H=W=128, K=9, PAD=1. NCHW fp32.
//
// lgkm-only barrier: LDS producer->consumer needs lgkmcnt(0) only; global
// prefetch loads stay in flight across it (vmcnt wait lands at the use).
#define BAR_LGKM()                                         \
  do {                                                     \
    asm volatile("s_waitcnt lgkmcnt(0)" ::: "memory");     \
    __builtin_amdgcn_s_barrier();                          \
  } while (0)

typedef __attribute__((ext_vector_type(8))) short bf16x8;
typedef __attribute__((ext_vector_type(4))) float f32x4;
typedef unsigned short u16;
typedef unsigned int u32;

// XCD-aware swizzle (verified round 4: FETCH 52.6 MB -> 12.7 MB).
__device__ __forceinline__ int swz_block(int bid) {
  return ((bid & 7) << 7) + (bid >> 3);
}

// Workspace layout (floats):
//   wm1  @ 0       (65536)  MFMA-packed bf16 weights L1: [pair32][nt4][term2][lane64][i8] u16
//   wm2  @ 65536   (65536)
//   wo1  @ 131072  (10368)  offset-conv weights L1, [c][t][j]
//   wo2  @ 141440  (10368)
//   bn1  @ 151808  (128)    scale[64], shift[64]
//   bn2  @ 151936  (128)
//   offb @ 152064  (1179648)
//   hbuf @ 1331712 (4194304)

// ---------------- prep: weight relayouts + BN constants ---------------------
__global__ __launch_bounds__(256) void prep_kernel(
    const float* __restrict__ w1, const float* __restrict__ w2,
    const float* __restrict__ woff1, const float* __restrict__ woff2,
    const float* __restrict__ g1, const float* __restrict__ be1,
    const float* __restrict__ m1, const float* __restrict__ v1,
    const float* __restrict__ g2, const float* __restrict__ be2,
    const float* __restrict__ m2, const float* __restrict__ v2,
    float* __restrict__ ws) {
  u16* wm1 = (u16*)ws;
  u16* wm2 = (u16*)(ws + 65536);
  float* wo1 = ws + 131072;
  float* wo2 = ws + 141440;
  float* bn1 = ws + 151808;
  float* bn2 = ws + 151936;
  int idx = blockIdx.x * 256 + threadIdx.x;
  if (idx < 131072) {
    // MFMA B-fragment packing. K per c-pair = 32: c = 2*pair + (k>=16),
    // kk = k&15 (0..8 real taps, 9..15 zero pad). B layout (16x16x32):
    // n(col o) = lane&15, k = (lane>>4)*8 + i. hi/lo bf16 split (RNE).
    int t = idx & 65535;
    const float* w = (idx < 65536) ? w1 : w2;
    u16* wm = (idx < 65536) ? wm1 : wm2;
    int i = t & 7;
    int lane = (t >> 3) & 63;
    int nt = (t >> 9) & 3;
    int pair = t >> 11;
    int k = ((lane >> 4) << 3) + i;
    int c = (pair << 1) + (k >> 4);
    int kk = k & 15;
    int o = (nt << 4) + (lane & 15);
    float val = (kk < 9) ? w[(o * 64 + c) * 9 + kk] : 0.f;
    u32 u = __float_as_uint(val);
    u32 r = u + 0x7FFFu + ((u >> 16) & 1u);
    u16 hi = (u16)(r >> 16);
    float lo = val - __uint_as_float(((u32)hi) << 16);
    u32 u2 = __float_as_uint(lo);
    u32 r2 = u2 + 0x7FFFu + ((u2 >> 16) & 1u);
    u16 lov = (u16)(r2 >> 16);
    size_t base = ((size_t)(pair * 4 + nt) * 2) * 512 + lane * 8 + i;
    wm[base] = hi;         // term 0 (hi)
    wm[base + 512] = lov;  // term 1 (lo)
  } else if (idx < 151808) {
    int u = idx - 131072;
    int t2 = (u < 10368) ? u : u - 10368;
    const float* w = (u < 10368) ? woff1 : woff2;
    float* wo = (u < 10368) ? wo1 : wo2;
    int j = t2 % 18;
    int v = t2 / 18;               // c*9 + t
    int tt = v % 9;
    int c = v / 9;
    wo[t2] = w[(j * 64 + c) * 9 + tt];
  } else if (idx < 151872) {
    int o = idx - 151808;
    float s = g1[o] * rsqrtf(v1[o] + 1e-5f);
    bn1[o] = s;
    bn1[64 + o] = be1[o] - m1[o] * s;
  } else if (idx < 151936) {
    int o = idx - 151872;
    float s = g2[o] * rsqrtf(v2[o] + 1e-5f);
    bn2[o] = s;
    bn2[64 + o] = be2[o] - m2[o] * s;
  }
}

// ---------------- offset conv: 3x3, 64 -> 18 ch, zero pad -------------------
// (round-4 version: s_load weights — the LDS-weight variant measured null)
__global__ __launch_bounds__(512, 8) void conv_off_kernel(
    const float* __restrict__ xin, const float* __restrict__ wofft,
    const float* __restrict__ boff, float* __restrict__ off) {
  __shared__ float halo[2][792];   // [buf][plane*198 + pos], 4 planes/stage
  int tid = threadIdx.x;
  int pxl = tid & 63;
  int og = tid >> 6;
  int ogu = __builtin_amdgcn_readfirstlane(og);
  int p0 = swz_block(blockIdx.x) * 64;
  int b = p0 >> 14, hw0 = p0 & 16383;
  int h = hw0 >> 7, w0 = hw0 & 127;

  bool sv = tid < 396;
  int pp = (tid >= 198) ? 1 : 0;
  int pos = tid - pp * 198;
  int r = pos / 66, cc = pos - r * 66;
  int yy = h + r - 1, xx = w0 + cc - 1;
  bool inb = sv && (yy >= 0) && (yy < 128) && (xx >= 0) && (xx < 128);
  int ofs = (yy << 7) + xx;
  const float* xb0 = xin + ((size_t)(b * 64) << 14);

  float stg0 = inb ? xb0[((size_t)pp << 14) + ofs] : 0.f;
  float stg1 = inb ? xb0[((size_t)(2 + pp) << 14) + ofs] : 0.f;

  int jbase = (ogu < 2) ? ogu * 3 : 6 + (ogu - 2) * 2;
  int nj = (ogu < 2) ? 3 : 2;
  int jc2 = jbase + 2;
  if (jc2 > 17) jc2 = 17;

  float acc[3] = {0.f, 0.f, 0.f};

#pragma unroll 1
  for (int cg = 0; cg < 64; cg += 4) {
    int bufi = (cg >> 2) & 1;
    if (sv) {
      halo[bufi][pp * 198 + pos] = stg0;
      halo[bufi][(2 + pp) * 198 + pos] = stg1;
    }
    if (cg < 60) {
      stg0 = inb ? xb0[((size_t)(cg + 4 + pp) << 14) + ofs] : 0.f;
      stg1 = inb ? xb0[((size_t)(cg + 6 + pp) << 14) + ofs] : 0.f;
    }
    BAR_LGKM();
    const float* hb = halo[bufi];
#pragma unroll
    for (int p = 0; p < 4; ++p) {
      const float* wc = wofft + (cg + p) * 162;
#pragma unroll
      for (int t = 0; t < 9; ++t) {
        float v = hb[p * 198 + (t / 3) * 66 + pxl + (t % 3)];
        acc[0] = fmaf(v, wc[t * 18 + jbase], acc[0]);
        acc[1] = fmaf(v, wc[t * 18 + jbase + 1], acc[1]);
        acc[2] = fmaf(v, wc[t * 18 + jc2], acc[2]);
      }
    }
  }
#pragma unroll
  for (int i = 0; i < 3; ++i) {
    if (i < nj) {
      int j = jbase + i;
      off[((size_t)(b * 18 + j) << 14) + hw0 + pxl] = acc[i] + boff[j];
    }
  }
}

// ---------------- fused deformable sample + MFMA einsum + BN + ReLU ---------
// Sampling = R7 path (folded coeffs, incrementing pointers, depth-1 prefetch).
// Einsum = per block a 64px x (64c x 16k-pad) x 64o GEMM on the matrix pipe:
// mfma_f32_16x16x32_bf16, one K=32 step per c-pair, 3-term bf16 split
// (Ah*Bh + Ah*Bl + Al*Bh; residual ~2^-17 rel). Weights arrive as per-lane
// fragments via coalesced global->LDS staging (no broadcast path at all).
// A layout: row(px)=lane&15, k=(lane>>4)*8+i; C/D: col(o)=lane&15,
// row(px)=(lane>>4)*4+reg (guide-verified).
__global__ __launch_bounds__(512, 6) void dcn_main_kernel(
    const float* __restrict__ xin, const float* __restrict__ off,
    const float* __restrict__ wmf, const float* __restrict__ bn,
    float* __restrict__ out) {
  __shared__ __align__(16) u16 Ah[2][64][40];   // [pairbuf][px][K 0..31, pad 40]
  __shared__ __align__(16) u16 Al[2][64][40];
  __shared__ __align__(16) u16 Bs[2][4096];     // [pairbuf][(nt*2+term)*512+lane*8+i]
  int tid = threadIdx.x;
  int lane = tid & 63;
  int wv = tid >> 6;
  int wvu = __builtin_amdgcn_readfirstlane(wv);
  int p0 = swz_block(blockIdx.x) * 64;
  int b = p0 >> 14, hw0 = p0 & 16383;
  int h = hw0 >> 7, w0 = hw0 & 127;
  const float* xb = xin + ((size_t)b << 20);
  const u16* wmu = (const u16*)wmf;

  bool act1 = (tid & 7) == 0;      // slot1 (k=8) handled by 1/8 of threads
  int s1 = 512 + (tid >> 3);
  int px1 = tid >> 3;              // slot1 px

  // --- per-slot params: folded coeffs + row pointers (R7 verbatim) ---
  float q[2][4];
  const float* pa[2];
  const float* pb[2];

#pragma unroll
  for (int j = 0; j < 2; ++j) {
    bool a = (j == 0) || act1;
    int s = (j == 0) ? tid : s1;
    int k = s >> 6;
    int pxs = s & 63;
    int hw = hw0 + pxs;
    float dy = a ? off[((size_t)(b * 18 + 2 * k) << 14) + hw] : 0.f;
    float dx = a ? off[((size_t)(b * 18 + 2 * k + 1) << 14) + hw] : 0.f;
    float py = (float)(h + k / 3 - 1) + dy;
    float pxf = (float)(w0 + pxs + k % 3 - 1) + dx;
    float y0f = floorf(py), x0f = floorf(pxf);
    float wy1 = py - y0f, wx1 = pxf - x0f;
    float wy0 = 1.f - wy1, wx0 = 1.f - wx1;
    int y0 = (int)y0f, x0 = (int)x0f;
    int y1 = y0 + 1, x1 = x0 + 1;
    bool vy0 = (y0 >= 0) && (y0 <= 127);
    bool vy1 = (y1 >= 0) && (y1 <= 127);
    bool vx0 = (x0 >= 0) && (x0 <= 127);
    bool vx1 = (x1 >= 0) && (x1 <= 127);
    float pw0 = (vy0 && vx0) ? wy0 * wx0 : 0.f;
    float pw1 = (vy0 && vx1) ? wy0 * wx1 : 0.f;
    float pw2 = (vy1 && vx0) ? wy1 * wx0 : 0.f;
    float pw3 = (vy1 && vx1) ? wy1 * wx1 : 0.f;
    int y0c = min(max(y0, 0), 127), y1c = min(max(y1, 0), 127);
    int xb2 = min(max(x0, 0), 126);
    bool se0 = (x0 == xb2);
    bool se1 = (x0 + 1 == xb2);
    q[j][0] = (se0 ? pw0 : 0.f) + (se1 ? pw1 : 0.f);
    q[j][1] = (se0 ? 0.f : pw0) + (se1 ? 0.f : pw1);
    q[j][2] = (se0 ? pw2 : 0.f) + (se1 ? pw3 : 0.f);
    q[j][3] = (se0 ? 0.f : pw2) + (se1 ? 0.f : pw3);
    pa[j] = xb + ((y0c << 7) + xb2);
    pb[j] = xb + ((y1c << 7) + xb2);
  }

  // zero the K-pad slots (kk 9..15 of both halves) once; never rewritten
  for (int z = tid; z < 3584; z += 512) {
    int m = z / 896;               // 0,1: Ah[0],Ah[1]; 2,3: Al[0],Al[1]
    int rr = z - m * 896;
    int px = rr / 14, jj = rr - (rr / 14) * 14;
    int k = (jj < 7) ? (9 + jj) : (18 + jj);   // 9..15, 25..31
    u16* bp = (m < 2) ? &Ah[m][0][0] : &Al[m - 2][0][0];
    bp[px * 40 + k] = 0;
  }

  // prologue: taps for c=0
  float2 t0a = *(const float2*)pa[0];
  float2 t1a = *(const float2*)pb[0];
  float2 t0b = act1 ? *(const float2*)pa[1] : make_float2(0.f, 0.f);
  float2 t1b = act1 ? *(const float2*)pb[1] : make_float2(0.f, 0.f);
  pa[0] += 16384; pb[0] += 16384; pa[1] += 16384; pb[1] += 16384;

  int mt = wvu >> 1;
  int ntb = (wvu & 1) * 2;
  int apx = mt * 16 + (lane & 15);
  int akf = (lane >> 4) * 8;

  f32x4 acc0 = {0.f, 0.f, 0.f, 0.f};
  f32x4 acc1 = {0.f, 0.f, 0.f, 0.f};
  uint4 bst = make_uint4(0, 0, 0, 0);

#pragma unroll 1
  for (int c = 0; c < 64; ++c) {
    int pbW = (c >> 1) & 1;
    int kh = (c & 1) << 4;
    // blend + bf16 split + A writes (slot0: px=lane, k=wv; slot1: px1, k=8)
    {
      float s = fmaf(q[0][0], t0a.x, fmaf(q[0][1], t0a.y,
                fmaf(q[0][2], t1a.x, q[0][3] * t1a.y)));
      u32 u = __float_as_uint(s);
      Ah[pbW][lane][kh + wv] = (u16)(u >> 16);
      float lo = s - __uint_as_float(u & 0xFFFF0000u);
      Al[pbW][lane][kh + wv] = (u16)(__float_as_uint(lo) >> 16);
    }
    if (act1) {
      float s = fmaf(q[1][0], t0b.x, fmaf(q[1][1], t0b.y,
                fmaf(q[1][2], t1b.x, q[1][3] * t1b.y)));
      u32 u = __float_as_uint(s);
      Ah[pbW][px1][kh + 8] = (u16)(u >> 16);
      float lo = s - __uint_as_float(u & 0xFFFF0000u);
      Al[pbW][px1][kh + 8] = (u16)(__float_as_uint(lo) >> 16);
    }
    // B staging: even phase issues the coalesced global load for pair c>>1;
    // odd phase writes it to LDS (vmcnt wait lands here, 1 phase of cover)
    if (!(c & 1)) {
      bst = *(const uint4*)(wmu + (size_t)(c >> 1) * 4096 + tid * 8);
    } else {
      *(uint4*)&Bs[pbW][tid * 8] = bst;
    }
    // prefetch taps c+1 (in flight across the lgkm barrier)
    if (c < 63) {
      t0a = *(const float2*)pa[0];
      t1a = *(const float2*)pb[0];
      if (act1) {
        t0b = *(const float2*)pa[1];
        t1b = *(const float2*)pb[1];
      }
      pa[0] += 16384; pb[0] += 16384; pa[1] += 16384; pb[1] += 16384;
    }
    BAR_LGKM();
    // pair complete on odd c: 6 MFMAs (2 N-tiles x 3 split terms)
    if (c & 1) {
      bf16x8 ah = *(const bf16x8*)&Ah[pbW][apx][akf];
      bf16x8 al = *(const bf16x8*)&Al[pbW][apx][akf];
      const u16* bsp = &Bs[pbW][0];
      bf16x8 b0h = *(const bf16x8*)(bsp + (ntb * 2 + 0) * 512 + lane * 8);
      bf16x8 b0l = *(const bf16x8*)(bsp + (ntb * 2 + 1) * 512 + lane * 8);
      bf16x8 b1h = *(const bf16x8*)(bsp + (ntb * 2 + 2) * 512 + lane * 8);
      bf16x8 b1l = *(const bf16x8*)(bsp + (ntb * 2 + 3) * 512 + lane * 8);
      acc0 = __builtin_amdgcn_mfma_f32_16x16x32_bf16(ah, b0h, acc0, 0, 0, 0);
      acc1 = __builtin_amdgcn_mfma_f32_16x16x32_bf16(ah, b1h, acc1, 0, 0, 0);
      acc0 = __builtin_amdgcn_mfma_f32_16x16x32_bf16(ah, b0l, acc0, 0, 0, 0);
      acc1 = __builtin_amdgcn_mfma_f32_16x16x32_bf16(ah, b1l, acc1, 0, 0, 0);
      acc0 = __builtin_amdgcn_mfma_f32_16x16x32_bf16(al, b0h, acc0, 0, 0, 0);
      acc1 = __builtin_amdgcn_mfma_f32_16x16x32_bf16(al, b1h, acc1, 0, 0, 0);
    }
  }

  // epilogue: C/D frag -> out. col(o)=lane&15, row(px)=(lane>>4)*4+reg.
  int o0 = ntb * 16 + (lane & 15);
  int prow = mt * 16 + ((lane >> 4) << 2);
  float sc0 = bn[o0], sh0 = bn[64 + o0];
  float sc1 = bn[16 + o0], sh1 = bn[80 + o0];
  float* ob0 = out + (((size_t)(b * 64 + o0)) << 14) + hw0 + prow;
  float* ob1 = out + (((size_t)(b * 64 + o0 + 16)) << 14) + hw0 + prow;
#pragma unroll
  for (int r = 0; r < 4; ++r) {
    ob0[r] = fmaxf(fmaf(acc0[r], sc0, sh0), 0.f);
    ob1[r] = fmaxf(fmaf(acc1[r], sc1, sh1), 0.f);
  }
}

extern "C" void kernel_launch(void* const* d_in, const int* in_sizes, int n_in,
                              void* d_out, int out_size, void* d_ws, size_t ws_size,
                              hipStream_t stream) {
  const float* x      = (const float*)d_in[0];
  const float* w_off1 = (const float*)d_in[1];
  const float* b_off1 = (const float*)d_in[2];
  const float* w1     = (const float*)d_in[3];
  const float* g1     = (const float*)d_in[4];
  const float* be1    = (const float*)d_in[5];
  const float* m1     = (const float*)d_in[6];
  const float* v1     = (const float*)d_in[7];
  const float* w_off2 = (const float*)d_in[8];
  const float* b_off2 = (const float*)d_in[9];
  const float* w2     = (const float*)d_in[10];
  const float* g2     = (const float*)d_in[11];
  const float* be2    = (const float*)d_in[12];
  const float* m2     = (const float*)d_in[13];
  const float* v2     = (const float*)d_in[14];
  float* out = (float*)d_out;

  float* ws   = (float*)d_ws;
  float* wm1  = ws;
  float* wm2  = ws + 65536;
  float* wo1  = ws + 131072;
  float* wo2  = ws + 141440;
  float* bn1  = ws + 151808;
  float* bn2  = ws + 151936;
  float* offb = ws + 152064;
  float* hbuf = ws + 1331712;

  prep_kernel<<<594, 256, 0, stream>>>(w1, w2, w_off1, w_off2,
                                       g1, be1, m1, v1, g2, be2, m2, v2, ws);

  conv_off_kernel<<<1024, 512, 0, stream>>>(x, wo1, b_off1, offb);
  dcn_main_kernel<<<1024, 512, 0, stream>>>(x, offb, wm1, bn1, hbuf);

  conv_off_kernel<<<1024, 512, 0, stream>>>(hbuf, wo2, b_off2, offb);
  dcn_main_kernel<<<1024, 512, 0, stream>>>(hbuf, offb, wm2, bn2, out);
}